// Round 2
// baseline (514.730 us; speedup 1.0000x reference)
//
#include <hip/hip_runtime.h>

// Decoder: 12 sequential steps of {attention over 12 enc timesteps, GRU cell, linear->scalar, feedback}.
// B=65536 batch elements fully independent -> single kernel, block owns 16 batch elems.
// Layout: 16 lanes per batch element, 4 hidden dims per lane (k = 4q..4q+3).
// GRU h@W_hh^T via mfma_f32_16x16x32_bf16 with BOTH operands split hi/lo bf16
// (hi*hi + hi*lo + lo*hi => ~2^-17 relative error, fp32-equivalent; R1 fix for absmax 6.36).

#define TT 12     // T_IN == T_OUT == 12
#define BB 65536
#define HH 64

typedef __bf16 bf16x8 __attribute__((ext_vector_type(8)));
typedef __bf16 bf16x4 __attribute__((ext_vector_type(4)));
typedef float  f32x4  __attribute__((ext_vector_type(4)));

__device__ __forceinline__ float sigm(float x){ return 1.0f/(1.0f+__expf(-x)); }
__device__ __forceinline__ float tanh_(float x){ return 1.0f - 2.0f/(__expf(2.0f*x)+1.0f); }

__global__ __launch_bounds__(256)
void decoder_kernel(const float* __restrict__ enc,    // (12,B,64)
                    const float* __restrict__ hid0,   // (B,64)
                    const float* __restrict__ last0,  // (B,3)
                    const float* __restrict__ Wih,    // (192,3)
                    const float* __restrict__ Whh,    // (192,64)
                    const float* __restrict__ bih,    // (192)
                    const float* __restrict__ bhh,    // (192)
                    const float* __restrict__ Wlin,   // (64)
                    const float* __restrict__ blin,   // (1)
                    float* __restrict__ out)          // (B,12)
{
    // LDS: hidden staged as bf16 hi/lo for MFMA A-frags (stride 72 bf16 = 144B, 16B-aligned rows),
    // gh output (stride 196 f32 kills store conflicts).
    __shared__ __align__(16) __bf16 sHi[16*72];
    __shared__ __align__(16) __bf16 sLo[16*72];
    __shared__ __align__(16) float  sGh[16*196];

    const int tid  = threadIdx.x;
    const int wv   = tid >> 6;        // wave 0..3
    const int lane = tid & 63;
    const int q    = lane & 15;       // position in 16-lane group / MFMA n or m index
    const int quad = lane >> 4;       // sub-group: which batch elem of this wave (attn phase)
    const int m    = wv*4 + quad;     // batch row within block, 0..15
    const size_t b = (size_t)blockIdx.x*16 + m;

    // ---- one-time loads ----
    // enc tile for this batch element: lane holds k=4q..4q+3 for all 12 t. 48 VGPRs, coalesced float4.
    f32x4 e4[TT];
    #pragma unroll
    for (int t=0;t<TT;++t)
        e4[t] = *(const f32x4*)(enc + ((size_t)t*BB + b)*HH + 4*q);

    f32x4 h = *(const f32x4*)(hid0 + b*HH + 4*q);
    float l0 = last0[b*3+0], l1 = last0[b*3+1], l2 = last0[b*3+2];

    // GRU input-side weights for this lane's 4 output dims per gate (gate order r,z,n)
    float wih[3][3][4];
    #pragma unroll
    for (int g=0; g<3; ++g)
        #pragma unroll
        for (int j=0;j<4;++j){
            int row = g*64 + 4*q + j;
            wih[g][0][j] = Wih[row*3+0];
            wih[g][1][j] = Wih[row*3+1];
            wih[g][2][j] = Wih[row*3+2];
        }
    float bc0[4], bc1[4], bi2[4], bh2[4];  // r,z biases fold (b_ih+b_hh); n needs them separate
    #pragma unroll
    for (int j=0;j<4;++j){
        bc0[j] = bih[0*64+4*q+j] + bhh[0*64+4*q+j];
        bc1[j] = bih[1*64+4*q+j] + bhh[1*64+4*q+j];
        bi2[j] = bih[2*64+4*q+j];
        bh2[j] = bhh[2*64+4*q+j];
    }
    f32x4 wl = *(const f32x4*)(Wlin + 4*q);
    float bl = blin[0];

    // W_hh^T B-fragments, hi/lo bf16 split, register-resident: wave covers N-chunks 3wv..3wv+2.
    // B-frag layout: n = lane&15, k = kc*32 + quad*8 + jj.
    bf16x8 wfhi[3][2], wflo[3][2];
    #pragma unroll
    for (int c=0;c<3;++c){
        int jout = (wv*3+c)*16 + q;
        #pragma unroll
        for (int kc=0;kc<2;++kc){
            const float* src = Whh + jout*64 + kc*32 + quad*8;
            bf16x8 vh, vl;
            #pragma unroll
            for (int jj=0;jj<8;++jj){
                float w = src[jj];
                __bf16 whi = (__bf16)w;
                vh[jj] = whi;
                vl[jj] = (__bf16)(w - (float)whi);
            }
            wfhi[c][kc] = vh;
            wflo[c][kc] = vl;
        }
    }

    // ---- 12 sequential decoder steps ----
    for (int s=0;s<TT;++s){
        // attention logits: dot(enc[t], h) over 64 dims = 4 local FMA + 4-stage butterfly in group
        float a[TT];
        #pragma unroll
        for (int t=0;t<TT;++t){
            float p = e4[t][0]*h[0] + e4[t][1]*h[1] + e4[t][2]*h[2] + e4[t][3]*h[3];
            p += __shfl_xor(p,1);
            p += __shfl_xor(p,2);
            p += __shfl_xor(p,4);
            p += __shfl_xor(p,8);
            a[t] = p;
        }
        float mx = a[0];
        #pragma unroll
        for (int t=1;t<TT;++t) mx = fmaxf(mx,a[t]);
        float ss = 0.f;
        #pragma unroll
        for (int t=0;t<TT;++t){ a[t] = __expf(a[t]-mx); ss += a[t]; }
        float inv = 1.0f/ss;
        // context accumulate + hidden update (hidden = hidden + context)
        #pragma unroll
        for (int t=0;t<TT;++t){
            float w = a[t]*inv;
            #pragma unroll
            for (int j=0;j<4;++j) h[j] += w * e4[t][j];
        }

        // stage h into LDS as bf16 hi + lo residual
        bf16x4 hhi, hlo;
        #pragma unroll
        for (int j=0;j<4;++j){
            hhi[j] = (__bf16)h[j];
            hlo[j] = (__bf16)(h[j] - (float)hhi[j]);
        }
        *(bf16x4*)&sHi[m*72 + 4*q] = hhi;
        *(bf16x4*)&sLo[m*72 + 4*q] = hlo;
        __syncthreads();

        // MFMA: gh[m][jout] = sum_k h[m][k] * Whh[jout][k], hi/lo cross terms (skip lo*lo).
        // A-frag (verified m120 layout): row = lane&15 (=q), k = quad*8 + kc*32.
        bf16x8 ahi0 = *(bf16x8*)&sHi[q*72 +  0 + quad*8];
        bf16x8 ahi1 = *(bf16x8*)&sHi[q*72 + 32 + quad*8];
        bf16x8 alo0 = *(bf16x8*)&sLo[q*72 +  0 + quad*8];
        bf16x8 alo1 = *(bf16x8*)&sLo[q*72 + 32 + quad*8];
        #pragma unroll
        for (int c=0;c<3;++c){
            f32x4 acc = {0.f,0.f,0.f,0.f};
            acc = __builtin_amdgcn_mfma_f32_16x16x32_bf16(ahi0, wfhi[c][0], acc, 0,0,0);
            acc = __builtin_amdgcn_mfma_f32_16x16x32_bf16(ahi1, wfhi[c][1], acc, 0,0,0);
            acc = __builtin_amdgcn_mfma_f32_16x16x32_bf16(ahi0, wflo[c][0], acc, 0,0,0);
            acc = __builtin_amdgcn_mfma_f32_16x16x32_bf16(ahi1, wflo[c][1], acc, 0,0,0);
            acc = __builtin_amdgcn_mfma_f32_16x16x32_bf16(alo0, wfhi[c][0], acc, 0,0,0);
            acc = __builtin_amdgcn_mfma_f32_16x16x32_bf16(alo1, wfhi[c][1], acc, 0,0,0);
            int jcol = (wv*3+c)*16 + q;
            // C/D layout (verified m89): col = lane&15, row = quad*4 + reg
            #pragma unroll
            for (int r=0;r<4;++r)
                sGh[(quad*4+r)*196 + jcol] = acc[r];
        }
        __syncthreads();

        // gates (lane's 4 dims). r=sig(i_r+h_r), z=sig(i_z+h_z),
        // n=tanh(i_n + r*h_n) with b_hh_n inside the r-multiply, h' = (1-z)*n + z*h.
        f32x4 ghr = *(f32x4*)&sGh[m*196 +   0 + 4*q];
        f32x4 ghz = *(f32x4*)&sGh[m*196 +  64 + 4*q];
        f32x4 ghn = *(f32x4*)&sGh[m*196 + 128 + 4*q];

        float o = 0.f;
        #pragma unroll
        for (int j=0;j<4;++j){
            float gr = bc0[j] + wih[0][0][j]*l0 + wih[0][1][j]*l1 + wih[0][2][j]*l2 + ghr[j];
            float gz = bc1[j] + wih[1][0][j]*l0 + wih[1][1][j]*l1 + wih[1][2][j]*l2 + ghz[j];
            float gn = bi2[j] + wih[2][0][j]*l0 + wih[2][1][j]*l1 + wih[2][2][j]*l2;
            float r = sigm(gr);
            float z = sigm(gz);
            float n = tanh_(gn + r*(ghn[j] + bh2[j]));
            float hn = (1.f - z)*n + z*h[j];
            h[j] = hn;
            o += hn * wl[j];
        }
        // out = h' . W_lin + b_lin, reduce over 16-lane group
        o += __shfl_xor(o,1);
        o += __shfl_xor(o,2);
        o += __shfl_xor(o,4);
        o += __shfl_xor(o,8);
        o += bl;
        if (q == 0) out[b*TT + s] = o;
        // last = [out, last[0], last[1]]
        l2 = l1; l1 = l0; l0 = o;
    }
}

extern "C" void kernel_launch(void* const* d_in, const int* in_sizes, int n_in,
                              void* d_out, int out_size, void* d_ws, size_t ws_size,
                              hipStream_t stream)
{
    const float* enc  = (const float*)d_in[0];
    const float* hid0 = (const float*)d_in[1];
    const float* lst  = (const float*)d_in[2];
    const float* Wih  = (const float*)d_in[3];
    const float* Whh  = (const float*)d_in[4];
    const float* bih  = (const float*)d_in[5];
    const float* bhh  = (const float*)d_in[6];
    const float* Wlin = (const float*)d_in[7];
    const float* blin = (const float*)d_in[8];
    decoder_kernel<<<BB/16, 256, 0, stream>>>(enc, hid0, lst, Wih, Whh, bih, bhh,
                                              Wlin, blin, (float*)d_out);
}

// Round 3
// 452.773 us; speedup vs baseline: 1.1368x; 1.1368x over previous
//
#include <hip/hip_runtime.h>

// Decoder: 12 sequential steps of {attention over 12 enc timesteps, GRU cell, linear->scalar, feedback}.
// B=65536 batch elements independent -> block owns 16 batch elems, 16 lanes per b, 4 dims per lane.
// R2: (a) matvec split bf16->fp16 hi/lo (2^-22 split error; R2 absmax was 0.4609/0.4625 - no margin),
//     (b) all 16-lane reductions via DPP row_ror rotate-reduce (VALU) instead of shfl_xor (DS latency).

#define TT 12     // T_IN == T_OUT == 12
#define BB 65536
#define HH 64

typedef _Float16 half8 __attribute__((ext_vector_type(8)));
typedef _Float16 half4 __attribute__((ext_vector_type(4)));
typedef float    f32x4 __attribute__((ext_vector_type(4)));

__device__ __forceinline__ float sigm(float x){ return 1.0f/(1.0f+__expf(-x)); }
__device__ __forceinline__ float tanh_(float x){ return 1.0f - 2.0f/(__expf(2.0f*x)+1.0f); }

// DPP row_ror rotate-reduce within the 16-lane row: after ror:1,2,4,8 every lane holds the row sum.
template<int N>
__device__ __forceinline__ float ror_add(float x){
    int s = __builtin_amdgcn_update_dpp(0, __float_as_int(x), 0x120+N, 0xF, 0xF, false);
    return x + __int_as_float(s);
}
__device__ __forceinline__ float sum16(float x){
    x = ror_add<1>(x); x = ror_add<2>(x); x = ror_add<4>(x); x = ror_add<8>(x);
    return x;
}

__global__ __launch_bounds__(256)
void decoder_kernel(const float* __restrict__ enc,    // (12,B,64)
                    const float* __restrict__ hid0,   // (B,64)
                    const float* __restrict__ last0,  // (B,3)
                    const float* __restrict__ Wih,    // (192,3)
                    const float* __restrict__ Whh,    // (192,64)
                    const float* __restrict__ bih,    // (192)
                    const float* __restrict__ bhh,    // (192)
                    const float* __restrict__ Wlin,   // (64)
                    const float* __restrict__ blin,   // (1)
                    float* __restrict__ out)          // (B,12)
{
    // LDS: hidden staged as fp16 hi/lo for MFMA A-frags (stride 72 halfs = 144B rows),
    // gh output (stride 196 f32).
    __shared__ __align__(16) _Float16 sHi[16*72];
    __shared__ __align__(16) _Float16 sLo[16*72];
    __shared__ __align__(16) float    sGh[16*196];

    const int tid  = threadIdx.x;
    const int wv   = tid >> 6;        // wave 0..3
    const int lane = tid & 63;
    const int q    = lane & 15;       // position in 16-lane group / MFMA n or m index
    const int quad = lane >> 4;       // which batch elem of this wave (attn phase)
    const int m    = wv*4 + quad;     // batch row within block, 0..15
    const size_t b = (size_t)blockIdx.x*16 + m;

    // ---- one-time loads ----
    f32x4 e4[TT];
    #pragma unroll
    for (int t=0;t<TT;++t)
        e4[t] = *(const f32x4*)(enc + ((size_t)t*BB + b)*HH + 4*q);

    f32x4 h = *(const f32x4*)(hid0 + b*HH + 4*q);
    float l0 = last0[b*3+0], l1 = last0[b*3+1], l2 = last0[b*3+2];

    // GRU input-side weights for this lane's 4 output dims per gate (gate order r,z,n)
    float wih[3][3][4];
    #pragma unroll
    for (int g=0; g<3; ++g)
        #pragma unroll
        for (int j=0;j<4;++j){
            int row = g*64 + 4*q + j;
            wih[g][0][j] = Wih[row*3+0];
            wih[g][1][j] = Wih[row*3+1];
            wih[g][2][j] = Wih[row*3+2];
        }
    float bc0[4], bc1[4], bi2[4], bh2[4];
    #pragma unroll
    for (int j=0;j<4;++j){
        bc0[j] = bih[0*64+4*q+j] + bhh[0*64+4*q+j];
        bc1[j] = bih[1*64+4*q+j] + bhh[1*64+4*q+j];
        bi2[j] = bih[2*64+4*q+j];
        bh2[j] = bhh[2*64+4*q+j];
    }
    f32x4 wl = *(const f32x4*)(Wlin + 4*q);
    float bl = blin[0];

    // W_hh^T B-fragments, hi/lo fp16 split, register-resident: wave covers N-chunks 3wv..3wv+2.
    // B-frag layout: n = lane&15, k = kc*32 + quad*8 + jj.
    half8 wfhi[3][2], wflo[3][2];
    #pragma unroll
    for (int c=0;c<3;++c){
        int jout = (wv*3+c)*16 + q;
        #pragma unroll
        for (int kc=0;kc<2;++kc){
            const float* src = Whh + jout*64 + kc*32 + quad*8;
            half8 vh, vl;
            #pragma unroll
            for (int jj=0;jj<8;++jj){
                float w = src[jj];
                _Float16 whi = (_Float16)w;
                vh[jj] = whi;
                vl[jj] = (_Float16)(w - (float)whi);
            }
            wfhi[c][kc] = vh;
            wflo[c][kc] = vl;
        }
    }

    // ---- 12 sequential decoder steps ----
    for (int s=0;s<TT;++s){
        // attention logits: dot(enc[t], h) = 4 local FMA + DPP rotate-reduce over 16 lanes
        float a[TT];
        #pragma unroll
        for (int t=0;t<TT;++t){
            float p = e4[t][0]*h[0] + e4[t][1]*h[1] + e4[t][2]*h[2] + e4[t][3]*h[3];
            a[t] = sum16(p);
        }
        float mx = a[0];
        #pragma unroll
        for (int t=1;t<TT;++t) mx = fmaxf(mx,a[t]);
        float ss = 0.f;
        #pragma unroll
        for (int t=0;t<TT;++t){ a[t] = __expf(a[t]-mx); ss += a[t]; }
        float inv = 1.0f/ss;
        #pragma unroll
        for (int t=0;t<TT;++t){
            float w = a[t]*inv;
            #pragma unroll
            for (int j=0;j<4;++j) h[j] += w * e4[t][j];
        }

        // stage h into LDS as fp16 hi + lo residual (~2^-22 combined)
        half4 hhi, hlo;
        #pragma unroll
        for (int j=0;j<4;++j){
            _Float16 hh = (_Float16)h[j];
            hhi[j] = hh;
            hlo[j] = (_Float16)(h[j] - (float)hh);
        }
        *(half4*)&sHi[m*72 + 4*q] = hhi;
        *(half4*)&sLo[m*72 + 4*q] = hlo;
        __syncthreads();

        // MFMA: gh[m][jout] = sum_k h[m][k] * Whh[jout][k]; terms hi*Whi + hi*Wlo + lo*Whi.
        // A-frag layout: row = lane&15 (=q), k = quad*8 + kc*32.
        half8 ahi0 = *(half8*)&sHi[q*72 +  0 + quad*8];
        half8 ahi1 = *(half8*)&sHi[q*72 + 32 + quad*8];
        half8 alo0 = *(half8*)&sLo[q*72 +  0 + quad*8];
        half8 alo1 = *(half8*)&sLo[q*72 + 32 + quad*8];
        #pragma unroll
        for (int c=0;c<3;++c){
            f32x4 acc = {0.f,0.f,0.f,0.f};
            acc = __builtin_amdgcn_mfma_f32_16x16x32_f16(ahi0, wfhi[c][0], acc, 0,0,0);
            acc = __builtin_amdgcn_mfma_f32_16x16x32_f16(ahi1, wfhi[c][1], acc, 0,0,0);
            acc = __builtin_amdgcn_mfma_f32_16x16x32_f16(ahi0, wflo[c][0], acc, 0,0,0);
            acc = __builtin_amdgcn_mfma_f32_16x16x32_f16(ahi1, wflo[c][1], acc, 0,0,0);
            acc = __builtin_amdgcn_mfma_f32_16x16x32_f16(alo0, wfhi[c][0], acc, 0,0,0);
            acc = __builtin_amdgcn_mfma_f32_16x16x32_f16(alo1, wfhi[c][1], acc, 0,0,0);
            int jcol = (wv*3+c)*16 + q;
            // C/D layout: col = lane&15, row = quad*4 + reg
            #pragma unroll
            for (int r=0;r<4;++r)
                sGh[(quad*4+r)*196 + jcol] = acc[r];
        }
        __syncthreads();

        // gates: r=sig(i_r+h_r), z=sig(i_z+h_z), n=tanh(i_n + r*(h_n+b_hh_n)), h'=(1-z)n+z*h
        f32x4 ghr = *(f32x4*)&sGh[m*196 +   0 + 4*q];
        f32x4 ghz = *(f32x4*)&sGh[m*196 +  64 + 4*q];
        f32x4 ghn = *(f32x4*)&sGh[m*196 + 128 + 4*q];

        float o = 0.f;
        #pragma unroll
        for (int j=0;j<4;++j){
            float gr = bc0[j] + wih[0][0][j]*l0 + wih[0][1][j]*l1 + wih[0][2][j]*l2 + ghr[j];
            float gz = bc1[j] + wih[1][0][j]*l0 + wih[1][1][j]*l1 + wih[1][2][j]*l2 + ghz[j];
            float gn = bi2[j] + wih[2][0][j]*l0 + wih[2][1][j]*l1 + wih[2][2][j]*l2;
            float r = sigm(gr);
            float z = sigm(gz);
            float n = tanh_(gn + r*(ghn[j] + bh2[j]));
            float hn = (1.f - z)*n + z*h[j];
            h[j] = hn;
            o += hn * wl[j];
        }
        // out = h' . W_lin + b_lin, DPP rotate-reduce over 16-lane group
        o = sum16(o) + bl;
        if (q == 0) out[b*TT + s] = o;
        // last = [out, last[0], last[1]]
        l2 = l1; l1 = l0; l0 = o;
    }
}

extern "C" void kernel_launch(void* const* d_in, const int* in_sizes, int n_in,
                              void* d_out, int out_size, void* d_ws, size_t ws_size,
                              hipStream_t stream)
{
    const float* enc  = (const float*)d_in[0];
    const float* hid0 = (const float*)d_in[1];
    const float* lst  = (const float*)d_in[2];
    const float* Wih  = (const float*)d_in[3];
    const float* Whh  = (const float*)d_in[4];
    const float* bih  = (const float*)d_in[5];
    const float* bhh  = (const float*)d_in[6];
    const float* Wlin = (const float*)d_in[7];
    const float* blin = (const float*)d_in[8];
    decoder_kernel<<<BB/16, 256, 0, stream>>>(enc, hid0, lst, Wih, Whh, bih, bhh,
                                              Wlin, blin, (float*)d_out);
}

// Round 4
// 444.201 us; speedup vs baseline: 1.1588x; 1.0193x over previous
//
#include <hip/hip_runtime.h>

// Decoder: 12 sequential steps of {attention over 12 enc timesteps, GRU cell, linear->scalar, feedback}.
// B=65536 batch elements independent -> block owns 16 batch elems, 16 lanes per b, 4 dims per lane.
// R4: kill register spills. R3 counters showed FETCH=107GB / WRITE=3.5GB (ideal: 0.42GB/3MB) ->
// scratch spill thrash (demand ~167 VGPR vs 120 allocated). Fix: per-q constants (wih/biases/wl,
// 56 regs) move to a block-shared LDS table (q-indexed, stride 60 dw for 16B alignment; lanes with
// equal q broadcast, q vs q+8 2-way alias = free), plus __launch_bounds__(256,3) -> 170-VGPR budget
// so the remaining ~145 demand fits spill-free at 3 waves/SIMD.

#define TT 12     // T_IN == T_OUT == 12
#define BB 65536
#define HH 64

typedef _Float16 half8 __attribute__((ext_vector_type(8)));
typedef _Float16 half4 __attribute__((ext_vector_type(4)));
typedef float    f32x4 __attribute__((ext_vector_type(4)));

__device__ __forceinline__ float sigm(float x){ return 1.0f/(1.0f+__expf(-x)); }
__device__ __forceinline__ float tanh_(float x){ return 1.0f - 2.0f/(__expf(2.0f*x)+1.0f); }

// DPP row_ror rotate-reduce within the 16-lane row: after ror:1,2,4,8 every lane holds the row sum.
template<int N>
__device__ __forceinline__ float ror_add(float x){
    int s = __builtin_amdgcn_update_dpp(0, __float_as_int(x), 0x120+N, 0xF, 0xF, false);
    return x + __int_as_float(s);
}
__device__ __forceinline__ float sum16(float x){
    x = ror_add<1>(x); x = ror_add<2>(x); x = ror_add<4>(x); x = ror_add<8>(x);
    return x;
}

#define CSTR 60   // sConst stride in dwords (16B-aligned b128 slots at 0,4,...,52)

__global__ __launch_bounds__(256, 3)
void decoder_kernel(const float* __restrict__ enc,    // (12,B,64)
                    const float* __restrict__ hid0,   // (B,64)
                    const float* __restrict__ last0,  // (B,3)
                    const float* __restrict__ Wih,    // (192,3)
                    const float* __restrict__ Whh,    // (192,64)
                    const float* __restrict__ bih,    // (192)
                    const float* __restrict__ bhh,    // (192)
                    const float* __restrict__ Wlin,   // (64)
                    const float* __restrict__ blin,   // (1)
                    float* __restrict__ out)          // (B,12)
{
    __shared__ __align__(16) _Float16 sHi[16*72];
    __shared__ __align__(16) _Float16 sLo[16*72];
    __shared__ __align__(16) float    sGh[16*196];
    // per-q constant table: [q][0..35]=wih[g][i][j] at g*12+i*4+j, [36..51]=bc0,bc1,bi2,bh2,
    // [52..55]=wl. Depends only on q=lane&15 -> one copy per block.
    __shared__ __align__(16) float    sConst[16*CSTR];

    const int tid  = threadIdx.x;
    const int wv   = tid >> 6;        // wave 0..3
    const int lane = tid & 63;
    const int q    = lane & 15;       // dim group / MFMA n or m index
    const int quad = lane >> 4;       // which batch elem of this wave (attn phase)
    const int m    = wv*4 + quad;     // batch row within block, 0..15
    const size_t b = (size_t)blockIdx.x*16 + m;

    // ---- stage per-q constants into LDS (one-time) ----
    for (int n = tid; n < 16*56; n += 256){
        int qq = n / 56, s = n % 56;
        float v;
        if (s < 36){
            int g = s/12, i = (s%12)/4, j = s%4;
            v = Wih[(g*64 + 4*qq + j)*3 + i];
        } else if (s < 52){
            int t2 = s - 36, which = t2/4, j = t2%4;
            if      (which == 0) v = bih[      4*qq+j] + bhh[      4*qq+j];
            else if (which == 1) v = bih[ 64 + 4*qq+j] + bhh[ 64 + 4*qq+j];
            else if (which == 2) v = bih[128 + 4*qq+j];
            else                 v = bhh[128 + 4*qq+j];
        } else {
            v = Wlin[4*qq + (s-52)];
        }
        sConst[qq*CSTR + s] = v;
    }

    // ---- one-time loads ----
    f32x4 e4[TT];
    #pragma unroll
    for (int t=0;t<TT;++t)
        e4[t] = *(const f32x4*)(enc + ((size_t)t*BB + b)*HH + 4*q);

    f32x4 h = *(const f32x4*)(hid0 + b*HH + 4*q);
    float l0 = last0[b*3+0], l1 = last0[b*3+1], l2 = last0[b*3+2];
    float bl = blin[0];

    // W_hh^T B-fragments, hi/lo fp16 split, register-resident: wave covers N-chunks 3wv..3wv+2.
    // B-frag layout: n = lane&15, k = kc*32 + quad*8 + jj.
    half8 wfhi[3][2], wflo[3][2];
    #pragma unroll
    for (int c=0;c<3;++c){
        int jout = (wv*3+c)*16 + q;
        #pragma unroll
        for (int kc=0;kc<2;++kc){
            const float* src = Whh + jout*64 + kc*32 + quad*8;
            half8 vh, vl;
            #pragma unroll
            for (int jj=0;jj<8;++jj){
                float w = src[jj];
                _Float16 whi = (_Float16)w;
                vh[jj] = whi;
                vl[jj] = (_Float16)(w - (float)whi);
            }
            wfhi[c][kc] = vh;
            wflo[c][kc] = vl;
        }
    }

    __syncthreads();   // sConst ready

    const float* cq = &sConst[q*CSTR];

    // ---- 12 sequential decoder steps ----
    for (int s=0;s<TT;++s){
        // attention logits: dot(enc[t], h) = 4 local FMA + DPP rotate-reduce over 16 lanes
        float a[TT];
        #pragma unroll
        for (int t=0;t<TT;++t){
            float p = e4[t][0]*h[0] + e4[t][1]*h[1] + e4[t][2]*h[2] + e4[t][3]*h[3];
            a[t] = sum16(p);
        }
        float mx = a[0];
        #pragma unroll
        for (int t=1;t<TT;++t) mx = fmaxf(mx,a[t]);
        float ss = 0.f;
        #pragma unroll
        for (int t=0;t<TT;++t){ a[t] = __expf(a[t]-mx); ss += a[t]; }
        float inv = 1.0f/ss;
        // context accumulate (unnormalized), then one scale by inv
        f32x4 ctx = {0.f,0.f,0.f,0.f};
        #pragma unroll
        for (int t=0;t<TT;++t){
            #pragma unroll
            for (int j=0;j<4;++j) ctx[j] += a[t] * e4[t][j];
        }
        #pragma unroll
        for (int j=0;j<4;++j) h[j] += ctx[j]*inv;

        // stage h into LDS as fp16 hi + lo residual (~2^-22 combined)
        half4 hhi, hlo;
        #pragma unroll
        for (int j=0;j<4;++j){
            _Float16 hh = (_Float16)h[j];
            hhi[j] = hh;
            hlo[j] = (_Float16)(h[j] - (float)hh);
        }
        *(half4*)&sHi[m*72 + 4*q] = hhi;
        *(half4*)&sLo[m*72 + 4*q] = hlo;
        __syncthreads();

        // MFMA: gh[m][jout] = sum_k h[m][k] * Whh[jout][k]; terms hi*Whi + hi*Wlo + lo*Whi.
        // A-frag layout: row = lane&15 (=q), k = quad*8 + kc*32.
        half8 ahi0 = *(half8*)&sHi[q*72 +  0 + quad*8];
        half8 ahi1 = *(half8*)&sHi[q*72 + 32 + quad*8];
        half8 alo0 = *(half8*)&sLo[q*72 +  0 + quad*8];
        half8 alo1 = *(half8*)&sLo[q*72 + 32 + quad*8];
        #pragma unroll
        for (int c=0;c<3;++c){
            f32x4 acc = {0.f,0.f,0.f,0.f};
            acc = __builtin_amdgcn_mfma_f32_16x16x32_f16(ahi0, wfhi[c][0], acc, 0,0,0);
            acc = __builtin_amdgcn_mfma_f32_16x16x32_f16(ahi1, wfhi[c][1], acc, 0,0,0);
            acc = __builtin_amdgcn_mfma_f32_16x16x32_f16(ahi0, wflo[c][0], acc, 0,0,0);
            acc = __builtin_amdgcn_mfma_f32_16x16x32_f16(ahi1, wflo[c][1], acc, 0,0,0);
            acc = __builtin_amdgcn_mfma_f32_16x16x32_f16(alo0, wfhi[c][0], acc, 0,0,0);
            acc = __builtin_amdgcn_mfma_f32_16x16x32_f16(alo1, wfhi[c][1], acc, 0,0,0);
            int jcol = (wv*3+c)*16 + q;
            // C/D layout: col = lane&15, row = quad*4 + reg
            #pragma unroll
            for (int r=0;r<4;++r)
                sGh[(quad*4+r)*196 + jcol] = acc[r];
        }
        __syncthreads();

        // gates: r=sig(i_r+h_r), z=sig(i_z+h_z), n=tanh(i_n + r*(h_n+b_hh_n)), h'=(1-z)n+z*h
        f32x4 ghr = *(f32x4*)&sGh[m*196 +   0 + 4*q];
        f32x4 ghz = *(f32x4*)&sGh[m*196 +  64 + 4*q];
        f32x4 ghn = *(f32x4*)&sGh[m*196 + 128 + 4*q];

        // per-q constants from LDS (b128 reads, broadcast across quads/waves)
        f32x4 wr0 = *(const f32x4*)(cq+ 0), wr1 = *(const f32x4*)(cq+ 4), wr2 = *(const f32x4*)(cq+ 8);
        f32x4 wz0 = *(const f32x4*)(cq+12), wz1 = *(const f32x4*)(cq+16), wz2 = *(const f32x4*)(cq+20);
        f32x4 wn0 = *(const f32x4*)(cq+24), wn1 = *(const f32x4*)(cq+28), wn2 = *(const f32x4*)(cq+32);
        f32x4 bc0 = *(const f32x4*)(cq+36), bc1 = *(const f32x4*)(cq+40);
        f32x4 bi2 = *(const f32x4*)(cq+44), bh2 = *(const f32x4*)(cq+48);
        f32x4 wl  = *(const f32x4*)(cq+52);

        float o = 0.f;
        #pragma unroll
        for (int j=0;j<4;++j){
            float gr = bc0[j] + wr0[j]*l0 + wr1[j]*l1 + wr2[j]*l2 + ghr[j];
            float gz = bc1[j] + wz0[j]*l0 + wz1[j]*l1 + wz2[j]*l2 + ghz[j];
            float gn = bi2[j] + wn0[j]*l0 + wn1[j]*l1 + wn2[j]*l2;
            float r = sigm(gr);
            float z = sigm(gz);
            float n = tanh_(gn + r*(ghn[j] + bh2[j]));
            float hn = (1.f - z)*n + z*h[j];
            h[j] = hn;
            o += hn * wl[j];
        }
        // out = h' . W_lin + b_lin, DPP rotate-reduce over 16-lane group
        o = sum16(o) + bl;
        if (q == 0) out[b*TT + s] = o;
        // last = [out, last[0], last[1]]
        l2 = l1; l1 = l0; l0 = o;
    }
}

extern "C" void kernel_launch(void* const* d_in, const int* in_sizes, int n_in,
                              void* d_out, int out_size, void* d_ws, size_t ws_size,
                              hipStream_t stream)
{
    const float* enc  = (const float*)d_in[0];
    const float* hid0 = (const float*)d_in[1];
    const float* lst  = (const float*)d_in[2];
    const float* Wih  = (const float*)d_in[3];
    const float* Whh  = (const float*)d_in[4];
    const float* bih  = (const float*)d_in[5];
    const float* bhh  = (const float*)d_in[6];
    const float* Wlin = (const float*)d_in[7];
    const float* blin = (const float*)d_in[8];
    decoder_kernel<<<BB/16, 256, 0, stream>>>(enc, hid0, lst, Wih, Whh, bih, bhh,
                                              Wlin, blin, (float*)d_out);
}

// Round 6
// 439.596 us; speedup vs baseline: 1.1709x; 1.0105x over previous
//
#include <hip/hip_runtime.h>

// Decoder: 12 sequential steps of {attention over 12 enc timesteps, GRU cell, linear->scalar, feedback}.
// B=65536 batch elements independent -> block owns 16 batch elems, 16 lanes per b, 4 dims per lane.
// R5b: VALU-issue-bound (VALUBusy 78%, HBM 5%, MFMA 9%). Fixes:
//  - __launch_bounds__(256,2): 256-VGPR budget; e4/wf/wih/biases ALL register-resident (demand ~190).
//    R4's VGPR_Count=84 vs ~166 demand meant AGPR shuttling (v_accvgpr_read per use) + per-step
//    LDS const reloads (can't hoist across barriers). Both eliminated.
//  - Packed fp32: ctx/dot/gate pre-activations as f32x4/f32x2 vector exprs -> v_pk_fma_f32.
//  - exp2-folded softmax (__builtin_amdgcn_exp2f -> v_exp_f32), pairwise-tree sums, dual ctx accums.

#define TT 12     // T_IN == T_OUT == 12
#define BB 65536
#define HH 64

typedef _Float16 half8 __attribute__((ext_vector_type(8)));
typedef _Float16 half4 __attribute__((ext_vector_type(4)));
typedef float    f32x4 __attribute__((ext_vector_type(4)));
typedef float    f32x2 __attribute__((ext_vector_type(2)));

#define L2E 1.44269504088896f

__device__ __forceinline__ float ex2(float x){ return __builtin_amdgcn_exp2f(x); }
__device__ __forceinline__ float sigm(float x){ return 1.0f/(1.0f + ex2(-L2E*x)); }
__device__ __forceinline__ float tanh_(float x){ return 1.0f - 2.0f/(ex2(2.0f*L2E*x)+1.0f); }

// DPP row_ror rotate-reduce within the 16-lane row: after ror:1,2,4,8 every lane holds the row sum.
template<int N>
__device__ __forceinline__ float ror_add(float x){
    int s = __builtin_amdgcn_update_dpp(0, __float_as_int(x), 0x120+N, 0xF, 0xF, false);
    return x + __int_as_float(s);
}
__device__ __forceinline__ float sum16(float x){
    x = ror_add<1>(x); x = ror_add<2>(x); x = ror_add<4>(x); x = ror_add<8>(x);
    return x;
}

__global__ __launch_bounds__(256, 2)
void decoder_kernel(const float* __restrict__ enc,    // (12,B,64)
                    const float* __restrict__ hid0,   // (B,64)
                    const float* __restrict__ last0,  // (B,3)
                    const float* __restrict__ Wih,    // (192,3)
                    const float* __restrict__ Whh,    // (192,64)
                    const float* __restrict__ bih,    // (192)
                    const float* __restrict__ bhh,    // (192)
                    const float* __restrict__ Wlin,   // (64)
                    const float* __restrict__ blin,   // (1)
                    float* __restrict__ out)          // (B,12)
{
    __shared__ __align__(16) _Float16 sHi[16*72];
    __shared__ __align__(16) _Float16 sLo[16*72];
    __shared__ __align__(16) float    sGh[16*196];

    const int tid  = threadIdx.x;
    const int wv   = tid >> 6;        // wave 0..3
    const int lane = tid & 63;
    const int q    = lane & 15;       // dim group / MFMA n or m index
    const int quad = lane >> 4;       // which batch elem of this wave (attn phase)
    const int m    = wv*4 + quad;     // batch row within block, 0..15
    const size_t b = (size_t)blockIdx.x*16 + m;

    // ---- one-time loads (all register-resident) ----
    f32x4 e4[TT];
    #pragma unroll
    for (int t=0;t<TT;++t)
        e4[t] = *(const f32x4*)(enc + ((size_t)t*BB + b)*HH + 4*q);

    f32x4 h = *(const f32x4*)(hid0 + b*HH + 4*q);
    float l0 = last0[b*3+0], l1 = last0[b*3+1], l2 = last0[b*3+2];
    float bl = blin[0];

    // GRU input-side weights for this lane's 4 output dims per gate (gate order r,z,n), as f32x4
    f32x4 wr0,wr1,wr2, wz0,wz1,wz2, wn0,wn1,wn2;
    {
        #pragma unroll
        for (int j=0;j<4;++j){
            int r0 = (0*64 + 4*q + j)*3, r1 = (1*64 + 4*q + j)*3, r2 = (2*64 + 4*q + j)*3;
            wr0[j]=Wih[r0+0]; wr1[j]=Wih[r0+1]; wr2[j]=Wih[r0+2];
            wz0[j]=Wih[r1+0]; wz1[j]=Wih[r1+1]; wz2[j]=Wih[r1+2];
            wn0[j]=Wih[r2+0]; wn1[j]=Wih[r2+1]; wn2[j]=Wih[r2+2];
        }
    }
    f32x4 bc0, bc1, bi2, bh2;
    #pragma unroll
    for (int j=0;j<4;++j){
        bc0[j] = bih[      4*q+j] + bhh[      4*q+j];
        bc1[j] = bih[ 64 + 4*q+j] + bhh[ 64 + 4*q+j];
        bi2[j] = bih[128 + 4*q+j];
        bh2[j] = bhh[128 + 4*q+j];
    }
    f32x4 wl = *(const f32x4*)(Wlin + 4*q);

    // W_hh^T B-fragments, hi/lo fp16 split, register-resident: wave covers N-chunks 3wv..3wv+2.
    // B-frag layout: n = lane&15, k = kc*32 + quad*8 + jj.
    half8 wfhi[3][2], wflo[3][2];
    #pragma unroll
    for (int c=0;c<3;++c){
        int jout = (wv*3+c)*16 + q;
        #pragma unroll
        for (int kc=0;kc<2;++kc){
            const float* src = Whh + jout*64 + kc*32 + quad*8;
            half8 vh, vl;
            #pragma unroll
            for (int jj=0;jj<8;++jj){
                float w = src[jj];
                _Float16 whi = (_Float16)w;
                vh[jj] = whi;
                vl[jj] = (_Float16)(w - (float)whi);
            }
            wfhi[c][kc] = vh;
            wflo[c][kc] = vl;
        }
    }

    // ---- 12 sequential decoder steps ----
    for (int s=0;s<TT;++s){
        // attention logits: packed dot (2x v_pk ops + horizontal add) + DPP rotate-reduce
        float a[TT];
        #pragma unroll
        for (int t=0;t<TT;++t){
            f32x2 p2 = e4[t].xy * h.xy;
            p2 += e4[t].zw * h.zw;
            a[t] = sum16(p2.x + p2.y);
        }
        // max (tree)
        float mx01 = fmaxf(a[0],a[1]), mx23 = fmaxf(a[2],a[3]), mx45 = fmaxf(a[4],a[5]);
        float mx67 = fmaxf(a[6],a[7]), mx89 = fmaxf(a[8],a[9]), mxab = fmaxf(a[10],a[11]);
        float mx = fmaxf(fmaxf(fmaxf(mx01,mx23),fmaxf(mx45,mx67)),fmaxf(mx89,mxab));
        float nm = -mx*L2E;
        #pragma unroll
        for (int t=0;t<TT;++t) a[t] = ex2(__builtin_fmaf(a[t], L2E, nm));
        // sum (tree)
        float s01=a[0]+a[1], s23=a[2]+a[3], s45=a[4]+a[5], s67=a[6]+a[7], s89=a[8]+a[9], sab=a[10]+a[11];
        float ss = ((s01+s23)+(s45+s67)) + (s89+sab);
        float inv = 1.0f/ss;
        // context: dual f32x4 accumulators (v_pk_fma_f32), then h += ctx*inv
        f32x4 ctxA = {0.f,0.f,0.f,0.f}, ctxB = {0.f,0.f,0.f,0.f};
        #pragma unroll
        for (int t=0;t<TT;t+=2){
            ctxA += e4[t]   * (f32x4)(a[t]);
            ctxB += e4[t+1] * (f32x4)(a[t+1]);
        }
        h += (ctxA + ctxB) * (f32x4)(inv);

        // stage h into LDS as fp16 hi + lo residual (~2^-22 combined)
        half4 hhi, hlo;
        #pragma unroll
        for (int j=0;j<4;++j){
            _Float16 hh = (_Float16)h[j];
            hhi[j] = hh;
            hlo[j] = (_Float16)(h[j] - (float)hh);
        }
        *(half4*)&sHi[m*72 + 4*q] = hhi;
        *(half4*)&sLo[m*72 + 4*q] = hlo;
        __syncthreads();

        // MFMA: gh[m][jout] = sum_k h[m][k] * Whh[jout][k]; terms hi*Whi + hi*Wlo + lo*Whi.
        // A-frag layout: row = lane&15 (=q), k = quad*8 + kc*32.
        half8 ahi0 = *(half8*)&sHi[q*72 +  0 + quad*8];
        half8 ahi1 = *(half8*)&sHi[q*72 + 32 + quad*8];
        half8 alo0 = *(half8*)&sLo[q*72 +  0 + quad*8];
        half8 alo1 = *(half8*)&sLo[q*72 + 32 + quad*8];
        #pragma unroll
        for (int c=0;c<3;++c){
            f32x4 acc = {0.f,0.f,0.f,0.f};
            acc = __builtin_amdgcn_mfma_f32_16x16x32_f16(ahi0, wfhi[c][0], acc, 0,0,0);
            acc = __builtin_amdgcn_mfma_f32_16x16x32_f16(ahi1, wfhi[c][1], acc, 0,0,0);
            acc = __builtin_amdgcn_mfma_f32_16x16x32_f16(ahi0, wflo[c][0], acc, 0,0,0);
            acc = __builtin_amdgcn_mfma_f32_16x16x32_f16(ahi1, wflo[c][1], acc, 0,0,0);
            acc = __builtin_amdgcn_mfma_f32_16x16x32_f16(alo0, wfhi[c][0], acc, 0,0,0);
            acc = __builtin_amdgcn_mfma_f32_16x16x32_f16(alo1, wfhi[c][1], acc, 0,0,0);
            int jcol = (wv*3+c)*16 + q;
            // C/D layout: col = lane&15, row = quad*4 + reg
            #pragma unroll
            for (int r=0;r<4;++r)
                sGh[(quad*4+r)*196 + jcol] = acc[r];
        }
        __syncthreads();

        // gates: r=sig(i_r+h_r), z=sig(i_z+h_z), n=tanh(i_n + r*(h_n+b_hh_n)), h'=(1-z)n+z*h
        f32x4 ghr = *(f32x4*)&sGh[m*196 +   0 + 4*q];
        f32x4 ghz = *(f32x4*)&sGh[m*196 +  64 + 4*q];
        f32x4 ghn = *(f32x4*)&sGh[m*196 + 128 + 4*q];

        // packed pre-activations
        f32x4 gr4 = bc0 + ghr;  gr4 += wr0*(f32x4)(l0); gr4 += wr1*(f32x4)(l1); gr4 += wr2*(f32x4)(l2);
        f32x4 gz4 = bc1 + ghz;  gz4 += wz0*(f32x4)(l0); gz4 += wz1*(f32x4)(l1); gz4 += wz2*(f32x4)(l2);
        f32x4 gn4 = bi2;        gn4 += wn0*(f32x4)(l0); gn4 += wn1*(f32x4)(l1); gn4 += wn2*(f32x4)(l2);
        f32x4 hb  = ghn + bh2;

        float o = 0.f;
        #pragma unroll
        for (int j=0;j<4;++j){
            float r = sigm(gr4[j]);
            float z = sigm(gz4[j]);
            float n = tanh_(gn4[j] + r*hb[j]);
            float hn = (1.f - z)*n + z*h[j];
            h[j] = hn;
            o += hn * wl[j];
        }
        // out = h' . W_lin + b_lin, DPP rotate-reduce over 16-lane group
        o = sum16(o) + bl;
        if (q == 0) out[b*TT + s] = o;
        // last = [out, last[0], last[1]]
        l2 = l1; l1 = l0; l0 = o;
    }
}

extern "C" void kernel_launch(void* const* d_in, const int* in_sizes, int n_in,
                              void* d_out, int out_size, void* d_ws, size_t ws_size,
                              hipStream_t stream)
{
    const float* enc  = (const float*)d_in[0];
    const float* hid0 = (const float*)d_in[1];
    const float* lst  = (const float*)d_in[2];
    const float* Wih  = (const float*)d_in[3];
    const float* Whh  = (const float*)d_in[4];
    const float* bih  = (const float*)d_in[5];
    const float* bhh  = (const float*)d_in[6];
    const float* Wlin = (const float*)d_in[7];
    const float* blin = (const float*)d_in[8];
    decoder_kernel<<<BB/16, 256, 0, stream>>>(enc, hid0, lst, Wih, Whh, bih, bhh,
                                              Wlin, blin, (float*)d_out);
}